// Round 3
// baseline (133.038 us; speedup 1.0000x reference)
//
#include <hip/hip_runtime.h>
#include <math.h>

// Problem constants
#define Bn 8
#define Cn 64
#define Hn 128
#define Wn 128
#define Rn 4

__device__ __forceinline__ float leaky(float x) { return x >= 0.f ? x : 0.1f * x; }

// ---------------------------------------------------------------------------
// Kernel A: per-batch precompute of dynamic depthwise kernels + channel attn,
// plus (block Bn) a transpose of w_conv -> wT[c][o].
//   kern_g[b][c][r][9] laid out as b*2304 + c*36 + r*9 + kk
//   att_g [b][r][c]    = sigmoid(sum_i a[b,r*16+i] * w_ca2[r,c,i])
// ---------------------------------------------------------------------------
__global__ __launch_bounds__(256) void precomp_kernel(
    const float* __restrict__ deg, const float* __restrict__ w_k1,
    const float* __restrict__ w_k2, const float* __restrict__ w_ca1,
    const float* __restrict__ w_ca2, const float* __restrict__ w_conv,
    float* __restrict__ kern_g, float* __restrict__ att_g,
    float* __restrict__ wT)
{
    const int tid = threadIdx.x;
    if (blockIdx.x == Bn) {                       // transpose w_conv (tiny)
        for (int f = tid; f < Cn * Cn; f += 256) {
            int o = f >> 6, c = f & 63;
            wT[c * 64 + o] = w_conv[f];
        }
        return;
    }
    const int b = blockIdx.x;
    __shared__ float y_s[64], a_s[64];
    if (tid < 64) {
        float sy = 0.f, sa = 0.f;
#pragma unroll 8
        for (int j = 0; j < 64; ++j) {
            float d = deg[b * 64 + j];
            sy += d * w_k1[tid * 64 + j];
            sa += d * w_ca1[tid * 64 + j];
        }
        y_s[tid] = leaky(sy);
        a_s[tid] = leaky(sa);
    }
    __syncthreads();
    // kern: 64*4*9 = 2304 values, each a 16-MAC dot
    for (int f = tid; f < Cn * Rn * 9; f += 256) {
        int c = f / 36;
        int j = f - c * 36;
        int r = j / 9;
        int kk = j - r * 9;
        int o = c * 9 + kk;                      // index into (576) dim of w_k2
        const float* wp = &w_k2[(r * 576 + o) * 16];
        const float* yp = &y_s[r * 16];
        float s = 0.f;
#pragma unroll
        for (int i = 0; i < 16; ++i) s += yp[i] * wp[i];
        kern_g[b * 2304 + f] = s;
    }
    // att: 4*64 = 256 values
    {
        int r = tid >> 6, o = tid & 63;
        const float* wp = &w_ca2[(r * 64 + o) * 16];
        const float* ap = &a_s[r * 16];
        float s = 0.f;
#pragma unroll
        for (int i = 0; i < 16; ++i) s += ap[i] * wp[i];
        att_g[b * 256 + tid] = 1.f / (1.f + expf(-s));
    }
}

// ---------------------------------------------------------------------------
// Main kernel: one block per (b,h) row, 256 threads = 4 waves.
// Wave = (oh, wq): oh = o-half (0..1), wq = w-half (0..1).
// Thread owns column w = wq*64 + lane; computes all 64 depthwise t_c for its
// column (duplicated across the 2 oh-waves) and accumulates its o-half of the
// 64x64 channel mix with wave-uniform SGPR weights. One barrier total.
// ---------------------------------------------------------------------------
__global__ __launch_bounds__(256, 4) void da_main(
    const float* __restrict__ x0, const float* __restrict__ q_map,
    const float* __restrict__ wT, const float* __restrict__ b_conv,
    const float* __restrict__ w_g1, const float* __restrict__ b_g1,
    const float* __restrict__ w_g2, const float* __restrict__ b_g2,
    const float* __restrict__ kern_g, const float* __restrict__ att_g,
    float* __restrict__ out)
{
    __shared__ __align__(16) float kern_lds[Cn * 48];   // [c][r][12] : 12 KB
    __shared__ float att_lds[Rn * 68];                  // [r][68]    : 1.1 KB

    const int tid = threadIdx.x;
    const int ob = blockIdx.x;
    // XCD-aware swizzle: XCD i gets batch i (4 MB image fits one L2).
    const int sb = ((ob & 7) << 7) | (ob >> 3);
    const int b = sb >> 7;
    const int h = sb & 127;

    const int lane = tid & 63;
    const int wq = (tid >> 6) & 1;
    const int oh = tid >> 7;
    const int w = wq * 64 + lane;

    // ---- stage kern + att ----
    for (int f = tid; f < Cn * Rn * 9; f += 256) {
        int c = f / 36;
        int j = f - c * 36;
        int r = j / 9;
        int kk = j - r * 9;
        kern_lds[c * 48 + r * 12 + kk] = kern_g[b * 2304 + f];
    }
    att_lds[(tid >> 6) * 68 + (tid & 63)] = att_g[b * 256 + tid];

    // ---- per-thread region routing (r1 for depthwise, r2 for CA) ----
    int r1, r2;
    {
        float q[9];
#pragma unroll
        for (int dh = 0; dh < 3; ++dh) {
            int row = h - 1 + dh;
#pragma unroll
            for (int dw = 0; dw < 3; ++dw) {
                int col = w - 1 + dw;
                q[dh * 3 + dw] = (row >= 0 && row < Hn && col >= 0 && col < Wn)
                                     ? q_map[(b * Hn + row) * Wn + col] : 0.f;
            }
        }
        float best1 = -1e30f, best2 = -1e30f;
        r1 = 0; r2 = 0;
#pragma unroll
        for (int r = 0; r < Rn; ++r) {
            float s1 = b_g1[r], s2 = b_g2[r];
#pragma unroll
            for (int k = 0; k < 9; ++k) {
                s1 += q[k] * w_g1[r * 9 + k];
                s2 += q[k] * w_g2[r * 9 + k];
            }
            if (s1 > best1) { best1 = s1; r1 = r; }   // strict > == first argmax
            if (s2 > best2) { best2 = s2; r2 = r; }
        }
    }
    __syncthreads();

    // ---- fused depthwise + channel-mix main loop (barrier-free) ----
    const bool okm = (h > 0);
    const bool okp = (h < Hn - 1);
    const bool mL = (w > 0);
    const bool mR = (w < Wn - 1);
    const int rowm = okm ? (h - 1) : h;      // clamped (value masked below)
    const int rowp = okp ? (h + 1) : h;
    const int wl = mL ? (w - 1) : w;
    const int wr_ = mR ? (w + 1) : w;

    float acc[32];
#pragma unroll
    for (int k = 0; k < 32; ++k) acc[k] = 0.f;

    const float* xbase = x0 + (size_t)(b * Cn) * Hn * Wn;
    const float* wTo = wT + oh * 32;

#pragma unroll 2
    for (int c = 0; c < Cn; ++c) {
        const float* xc = xbase + c * (Hn * Wn);
        const float* rm = xc + rowm * Wn;
        const float* r0 = xc + h * Wn;
        const float* rp = xc + rowp * Wn;
        float a0 = rm[wl], a1 = rm[w], a2 = rm[wr_];
        float b0 = r0[wl], b1 = r0[w], b2 = r0[wr_];
        float c0 = rp[wl], c1 = rp[w], c2 = rp[wr_];
        if (!okm) { a0 = 0.f; a1 = 0.f; a2 = 0.f; }   // block-uniform
        if (!okp) { c0 = 0.f; c1 = 0.f; c2 = 0.f; }
        if (!mL)  { a0 = 0.f; b0 = 0.f; c0 = 0.f; }   // per-lane cndmask
        if (!mR)  { a2 = 0.f; b2 = 0.f; c2 = 0.f; }

        const float* kp = &kern_lds[c * 48 + r1 * 12];     // 4 distinct banks
        float4 k03 = *(const float4*)kp;
        float4 k47 = *(const float4*)(kp + 4);
        float k8 = kp[8];
        float t = a0 * k03.x + a1 * k03.y + a2 * k03.z
                + b0 * k03.w + b1 * k47.x + b2 * k47.y
                + c0 * k47.z + c1 * k47.w + c2 * k8;
        t = leaky(t);

        const float* wr2 = wTo + c * 64;                   // wave-uniform -> s_load
#pragma unroll
        for (int k = 0; k < 32; ++k) acc[k] += t * wr2[k];
    }

    // ---- epilogue: bias + CA branch + coalesced store ----
    const float* xout = x0 + ((size_t)(b * Cn + oh * 32) * Hn + h) * Wn + w;
    float* oout = out + ((size_t)(b * Cn + oh * 32) * Hn + h) * Wn + w;
    const float* attp = &att_lds[r2 * 68 + oh * 32];
#pragma unroll
    for (int k = 0; k < 32; ++k) {
        const int o = oh * 32 + k;
        float xv = xout[k * (Hn * Wn)];                    // guaranteed L2 hit
        float res = acc[k] + b_conv[o] + xv * attp[k];
        oout[k * (Hn * Wn)] = res;                         // 256B coalesced
    }
}

// ---------------------------------------------------------------------------
extern "C" void kernel_launch(void* const* d_in, const int* in_sizes, int n_in,
                              void* d_out, int out_size, void* d_ws, size_t ws_size,
                              hipStream_t stream)
{
    const float* x0     = (const float*)d_in[0];
    const float* deg    = (const float*)d_in[1];
    const float* q_map  = (const float*)d_in[2];
    const float* w_k1   = (const float*)d_in[3];
    const float* w_k2   = (const float*)d_in[4];
    const float* w_conv = (const float*)d_in[5];
    const float* b_conv = (const float*)d_in[6];
    const float* w_ca1  = (const float*)d_in[7];
    const float* w_ca2  = (const float*)d_in[8];
    const float* w_g1   = (const float*)d_in[9];
    const float* b_g1   = (const float*)d_in[10];
    const float* w_g2   = (const float*)d_in[11];
    const float* b_g2   = (const float*)d_in[12];
    float* outp   = (float*)d_out;
    float* kern_g = (float*)d_ws;                 // 8*2304 floats
    float* att_g  = kern_g + Bn * Cn * Rn * 9;    // 8*256  floats
    float* wT     = att_g + Bn * 256;             // 4096   floats

    precomp_kernel<<<Bn + 1, 256, 0, stream>>>(deg, w_k1, w_k2, w_ca1, w_ca2,
                                               w_conv, kern_g, att_g, wT);
    da_main<<<Bn * Hn, 256, 0, stream>>>(x0, q_map, wT, b_conv,
                                         w_g1, b_g1, w_g2, b_g2,
                                         kern_g, att_g, outp);
}

// Round 4
// 74.898 us; speedup vs baseline: 1.7762x; 1.7762x over previous
//
#include <hip/hip_runtime.h>
#include <math.h>

// Problem constants
#define Bn 8
#define Cn 64
#define Hn 128
#define Wn 128
#define Rn 4

__device__ __forceinline__ float leaky(float x) { return x >= 0.f ? x : 0.1f * x; }

// ---------------------------------------------------------------------------
// Kernel A: per-batch precompute of dynamic depthwise kernels + channel attn,
// plus (block Bn) a transpose of w_conv -> wT[c][o].
//   kern_g[b][c][r][9] laid out as b*2304 + c*36 + r*9 + kk
//   att_g [b][r][c]    = sigmoid(sum_i a[b,r*16+i] * w_ca2[r,c,i])
// ---------------------------------------------------------------------------
__global__ __launch_bounds__(256) void precomp_kernel(
    const float* __restrict__ deg, const float* __restrict__ w_k1,
    const float* __restrict__ w_k2, const float* __restrict__ w_ca1,
    const float* __restrict__ w_ca2, const float* __restrict__ w_conv,
    float* __restrict__ kern_g, float* __restrict__ att_g,
    float* __restrict__ wT)
{
    const int tid = threadIdx.x;
    if (blockIdx.x == Bn) {                       // transpose w_conv (tiny)
        for (int f = tid; f < Cn * Cn; f += 256) {
            int o = f >> 6, c = f & 63;
            wT[c * 64 + o] = w_conv[f];
        }
        return;
    }
    const int b = blockIdx.x;
    __shared__ float y_s[64], a_s[64];
    if (tid < 64) {
        float sy = 0.f, sa = 0.f;
#pragma unroll 8
        for (int j = 0; j < 64; ++j) {
            float d = deg[b * 64 + j];
            sy += d * w_k1[tid * 64 + j];
            sa += d * w_ca1[tid * 64 + j];
        }
        y_s[tid] = leaky(sy);
        a_s[tid] = leaky(sa);
    }
    __syncthreads();
    // kern: 64*4*9 = 2304 values, each a 16-MAC dot
    for (int f = tid; f < Cn * Rn * 9; f += 256) {
        int c = f / 36;
        int j = f - c * 36;
        int r = j / 9;
        int kk = j - r * 9;
        int o = c * 9 + kk;                      // index into (576) dim of w_k2
        const float* wp = &w_k2[(r * 576 + o) * 16];
        const float* yp = &y_s[r * 16];
        float s = 0.f;
#pragma unroll
        for (int i = 0; i < 16; ++i) s += yp[i] * wp[i];
        kern_g[b * 2304 + f] = s;
    }
    // att: 4*64 = 256 values
    {
        int r = tid >> 6, o = tid & 63;
        const float* wp = &w_ca2[(r * 64 + o) * 16];
        const float* ap = &a_s[r * 16];
        float s = 0.f;
#pragma unroll
        for (int i = 0; i < 16; ++i) s += ap[i] * wp[i];
        att_g[b * 256 + tid] = 1.f / (1.f + expf(-s));
    }
}

// ---------------------------------------------------------------------------
// Main kernel: one block per (b,h) row, 256 threads = 4 waves.
// Wave = (oh, wq): oh = o-half, wq = w-half. Thread owns column w = wq*64+lane,
// computes all 64 depthwise t_c for its column (taps: 3 coalesced loads +
// 6 shfl), and accumulates its 32-o half of the channel mix with weights
// broadcast-read from LDS (pure in-order DS inner loop, zero SMEM, 1 barrier).
// ---------------------------------------------------------------------------
__global__ __launch_bounds__(256, 4) void da_main(
    const float* __restrict__ x0, const float* __restrict__ q_map,
    const float* __restrict__ wT, const float* __restrict__ b_conv,
    const float* __restrict__ w_g1, const float* __restrict__ b_g1,
    const float* __restrict__ w_g2, const float* __restrict__ b_g2,
    const float* __restrict__ kern_g, const float* __restrict__ att_g,
    float* __restrict__ out)
{
    __shared__ __align__(16) float kern_lds[Cn * 48];   // [c][r][12] : 12 KB
    __shared__ __align__(16) float wc_lds[Cn * 68];     // [c][o]+pad : 17 KB
    __shared__ float att_lds[Rn * 68];                  // [r][o]     : 1.1 KB

    const int tid = threadIdx.x;
    const int ob = blockIdx.x;
    // XCD-aware swizzle: XCD i gets batch i (4 MB image fits one L2).
    const int sb = ((ob & 7) << 7) | (ob >> 3);
    const int b = sb >> 7;
    const int h = sb & 127;

    const int lane = tid & 63;
    const int wq = (tid >> 6) & 1;
    const int oh = tid >> 7;
    const int w = wq * 64 + lane;

    // ---- stage kern + wconv^T + att ----
    for (int f = tid; f < Cn * Rn * 9; f += 256) {
        int c = f / 36;
        int j = f - c * 36;
        int r = j / 9;
        int kk = j - r * 9;
        kern_lds[c * 48 + r * 12 + kk] = kern_g[b * 2304 + f];
    }
    for (int f = tid; f < Cn * Cn; f += 256) {
        int c = f >> 6, o = f & 63;
        wc_lds[c * 68 + o] = wT[f];                     // wT already [c][o]
    }
    att_lds[(tid >> 6) * 68 + (tid & 63)] = att_g[b * 256 + tid];

    // ---- per-thread region routing (r1 for depthwise, r2 for CA) ----
    int r1, r2;
    {
        float q[9];
#pragma unroll
        for (int dh = 0; dh < 3; ++dh) {
            int row = h - 1 + dh;
#pragma unroll
            for (int dw = 0; dw < 3; ++dw) {
                int col = w - 1 + dw;
                q[dh * 3 + dw] = (row >= 0 && row < Hn && col >= 0 && col < Wn)
                                     ? q_map[(b * Hn + row) * Wn + col] : 0.f;
            }
        }
        float best1 = -1e30f, best2 = -1e30f;
        r1 = 0; r2 = 0;
#pragma unroll
        for (int r = 0; r < Rn; ++r) {
            float s1 = b_g1[r], s2 = b_g2[r];
#pragma unroll
            for (int k = 0; k < 9; ++k) {
                s1 += q[k] * w_g1[r * 9 + k];
                s2 += q[k] * w_g2[r * 9 + k];
            }
            if (s1 > best1) { best1 = s1; r1 = r; }   // strict > == first argmax
            if (s2 > best2) { best2 = s2; r2 = r; }
        }
    }
    __syncthreads();

    // ---- fused depthwise + channel-mix main loop (barrier-free) ----
    const bool okm = (h > 0);
    const bool okp = (h < Hn - 1);

    float acc[32];
#pragma unroll
    for (int k = 0; k < 32; ++k) acc[k] = 0.f;

    const float* xbase = x0 + (size_t)(b * Cn) * Hn * Wn + h * Wn + w;
    const float* wlds = wc_lds + oh * 32;

#pragma unroll 2
    for (int c = 0; c < Cn; ++c) {
        const float* xc = xbase + c * (Hn * Wn);
        float vm = okm ? xc[-Wn] : 0.f;
        float v0 = xc[0];
        float vp = okp ? xc[Wn] : 0.f;
        float lm = __shfl_up(vm, 1), l0 = __shfl_up(v0, 1), lp = __shfl_up(vp, 1);
        float rm = __shfl_down(vm, 1), r0 = __shfl_down(v0, 1), rp = __shfl_down(vp, 1);
        if (lane == 0) {                 // left edge of this wave's w-range
            if (w == 0) { lm = 0.f; l0 = 0.f; lp = 0.f; }
            else { lm = okm ? xc[-1 - Wn] : 0.f; l0 = xc[-1]; lp = okp ? xc[-1 + Wn] : 0.f; }
        }
        if (lane == 63) {                // right edge
            if (w == 127) { rm = 0.f; r0 = 0.f; rp = 0.f; }
            else { rm = okm ? xc[1 - Wn] : 0.f; r0 = xc[1]; rp = okp ? xc[1 + Wn] : 0.f; }
        }
        const float* kp = &kern_lds[c * 48 + r1 * 12];   // 4-addr multicast, bank-disjoint
        float4 k03 = *(const float4*)kp;
        float4 k47 = *(const float4*)(kp + 4);
        float k8 = kp[8];
        float t = lm * k03.x + vm * k03.y + rm * k03.z
                + l0 * k03.w + v0 * k47.x + r0 * k47.y
                + lp * k47.z + vp * k47.w + rp * k8;
        t = leaky(t);

        const float* wrow = wlds + c * 68;               // wave-uniform -> broadcast
#pragma unroll
        for (int k4 = 0; k4 < 8; ++k4) {
            float4 wv = *(const float4*)(wrow + k4 * 4);
            acc[k4 * 4 + 0] += t * wv.x;
            acc[k4 * 4 + 1] += t * wv.y;
            acc[k4 * 4 + 2] += t * wv.z;
            acc[k4 * 4 + 3] += t * wv.w;
        }
    }

    // ---- epilogue: bias + CA branch + coalesced store ----
    const float* xout = x0 + ((size_t)(b * Cn + oh * 32) * Hn + h) * Wn + w;
    float* oout = out + ((size_t)(b * Cn + oh * 32) * Hn + h) * Wn + w;
    const float* attp = &att_lds[r2 * 68 + oh * 32];
#pragma unroll
    for (int k = 0; k < 32; ++k) {
        const int o = oh * 32 + k;
        float xv = xout[k * (Hn * Wn)];                  // L2 hit
        float res = acc[k] + b_conv[o] + xv * attp[k];
        oout[k * (Hn * Wn)] = res;                       // 256B coalesced
    }
}

// ---------------------------------------------------------------------------
extern "C" void kernel_launch(void* const* d_in, const int* in_sizes, int n_in,
                              void* d_out, int out_size, void* d_ws, size_t ws_size,
                              hipStream_t stream)
{
    const float* x0     = (const float*)d_in[0];
    const float* deg    = (const float*)d_in[1];
    const float* q_map  = (const float*)d_in[2];
    const float* w_k1   = (const float*)d_in[3];
    const float* w_k2   = (const float*)d_in[4];
    const float* w_conv = (const float*)d_in[5];
    const float* b_conv = (const float*)d_in[6];
    const float* w_ca1  = (const float*)d_in[7];
    const float* w_ca2  = (const float*)d_in[8];
    const float* w_g1   = (const float*)d_in[9];
    const float* b_g1   = (const float*)d_in[10];
    const float* w_g2   = (const float*)d_in[11];
    const float* b_g2   = (const float*)d_in[12];
    float* outp   = (float*)d_out;
    float* kern_g = (float*)d_ws;                 // 8*2304 floats
    float* att_g  = kern_g + Bn * Cn * Rn * 9;    // 8*256  floats
    float* wT     = att_g + Bn * 256;             // 4096   floats

    precomp_kernel<<<Bn + 1, 256, 0, stream>>>(deg, w_k1, w_k2, w_ca1, w_ca2,
                                               w_conv, kern_g, att_g, wT);
    da_main<<<Bn * Hn, 256, 0, stream>>>(x0, q_map, wT, b_conv,
                                         w_g1, b_g1, w_g2, b_g2,
                                         kern_g, att_g, outp);
}

// Round 5
// 45.675 us; speedup vs baseline: 2.9127x; 1.6398x over previous
//
#include <hip/hip_runtime.h>
#include <hip/hip_bf16.h>
#include <math.h>

// Problem constants
#define Bn 8
#define Cn 64
#define Hn 128
#define Wn 128
#define Rn 4

typedef __bf16 v8bf __attribute__((ext_vector_type(8)));
typedef float  v16f __attribute__((ext_vector_type(16)));

__device__ __forceinline__ float leaky(float x) { return x >= 0.f ? x : 0.1f * x; }

__device__ __forceinline__ unsigned short bf16bits(float x) {
    __hip_bfloat16 h = __float2bfloat16(x);
    return *reinterpret_cast<unsigned short*>(&h);
}

// ---------------------------------------------------------------------------
// Kernel A: per-batch dynamic depthwise kernels + channel attn; block Bn
// converts w_conv -> bf16 (kept [o][c], the MFMA A layout).
//   kern_g[b][c][r][9]  (b*2304 + c*36 + r*9 + kk)
//   att_g [b][r][c]
// ---------------------------------------------------------------------------
__global__ __launch_bounds__(256) void precomp_kernel(
    const float* __restrict__ deg, const float* __restrict__ w_k1,
    const float* __restrict__ w_k2, const float* __restrict__ w_ca1,
    const float* __restrict__ w_ca2, const float* __restrict__ w_conv,
    float* __restrict__ kern_g, float* __restrict__ att_g,
    unsigned short* __restrict__ wbf)
{
    const int tid = threadIdx.x;
    if (blockIdx.x == Bn) {                       // w_conv -> bf16
        for (int f = tid; f < Cn * Cn; f += 256)
            wbf[f] = bf16bits(w_conv[f]);
        return;
    }
    const int b = blockIdx.x;
    __shared__ float y_s[64], a_s[64];
    if (tid < 64) {
        float sy = 0.f, sa = 0.f;
#pragma unroll 8
        for (int j = 0; j < 64; ++j) {
            float d = deg[b * 64 + j];
            sy += d * w_k1[tid * 64 + j];
            sa += d * w_ca1[tid * 64 + j];
        }
        y_s[tid] = leaky(sy);
        a_s[tid] = leaky(sa);
    }
    __syncthreads();
    for (int f = tid; f < Cn * Rn * 9; f += 256) {
        int c = f / 36;
        int j = f - c * 36;
        int r = j / 9;
        int kk = j - r * 9;
        int o = c * 9 + kk;
        const float* wp = &w_k2[(r * 576 + o) * 16];
        const float* yp = &y_s[r * 16];
        float s = 0.f;
#pragma unroll
        for (int i = 0; i < 16; ++i) s += yp[i] * wp[i];
        kern_g[b * 2304 + f] = s;
    }
    {
        int r = tid >> 6, o = tid & 63;
        const float* wp = &w_ca2[(r * 64 + o) * 16];
        const float* ap = &a_s[r * 16];
        float s = 0.f;
#pragma unroll
        for (int i = 0; i < 16; ++i) s += ap[i] * wp[i];
        att_g[b * 256 + tid] = 1.f / (1.f + expf(-s));
    }
}

// ---------------------------------------------------------------------------
// Main kernel: one block per (b,h) row, 256 threads = 4 waves, 2 barriers.
// Phase 1: thread (w = tid&127, half = tid>>7) computes t[c][w] for 32 c
//          (taps: 3 coalesced loads + 6 shfl), packs bf16 pairs into
//          XOR-swizzled t_lds[w][c].
// Phase 2: wave n owns w-tile [32n,32n+32); out(64x32) = w_conv(64x64,bf16) x
//          t(64x32,bf16) via 8 x mfma_f32_32x32x16_bf16; epilogue fuses
//          bias + x0*att[r2] and stores.
// ---------------------------------------------------------------------------
__global__ __launch_bounds__(256, 4) void da_main(
    const float* __restrict__ x0, const float* __restrict__ q_map,
    const unsigned short* __restrict__ wbf, const float* __restrict__ b_conv,
    const float* __restrict__ w_g1, const float* __restrict__ b_g1,
    const float* __restrict__ w_g2, const float* __restrict__ b_g2,
    const float* __restrict__ kern_g, const float* __restrict__ att_g,
    float* __restrict__ out)
{
    __shared__ __align__(16) float kern_lds[Cn * 48];            // 12 KB
    __shared__ __align__(16) unsigned short wc_lds[Cn * Cn];     // 8 KB  (swizzled [o][c])
    __shared__ __align__(16) unsigned short t_lds[Wn * Cn];      // 16 KB (swizzled [w][c])
    __shared__ float att_lds[Rn * 68];                           // 1.1 KB
    __shared__ float bias_lds[Cn];                               // 0.25 KB
    __shared__ int   ridx2[Wn];                                  // 0.5 KB

    const int tid = threadIdx.x;
    const int ob = blockIdx.x;
    // XCD-aware swizzle: XCD i gets batch i (4 MB image == one L2).
    const int sb = ((ob & 7) << 7) | (ob >> 3);
    const int b = sb >> 7;
    const int h = sb & 127;

    const int lane = tid & 63;
    const int w = tid & 127;
    const int half = tid >> 7;

    // ---- phase 0: staging ----
    for (int f = tid; f < Cn * Rn * 9; f += 256) {
        int c = f / 36;
        int j = f - c * 36;
        int r = j / 9;
        int kk = j - r * 9;
        kern_lds[c * 48 + r * 12 + kk] = kern_g[b * 2304 + f];
    }
    {   // wc: swizzled bf16 [o][c]; dword f -> o=f>>5, cbyte=4*(f&31)
        const unsigned* src = (const unsigned*)wbf;
        for (int f = tid; f < Cn * Cn / 2; f += 256) {
            int o = f >> 5;
            int cbyte = (f & 31) * 4;
            *(unsigned*)((char*)wc_lds + o * 128 + (cbyte ^ ((o & 7) << 4))) = src[f];
        }
    }
    att_lds[(tid >> 6) * 68 + (tid & 63)] = att_g[b * 256 + tid];
    if (tid < 64) bias_lds[tid] = b_conv[tid];

    // region routing for this thread's column w (both halves compute; half 0
    // publishes r2)
    int r1;
    {
        float q[9];
#pragma unroll
        for (int dh = 0; dh < 3; ++dh) {
            int row = h - 1 + dh;
#pragma unroll
            for (int dw = 0; dw < 3; ++dw) {
                int col = w - 1 + dw;
                q[dh * 3 + dw] = (row >= 0 && row < Hn && col >= 0 && col < Wn)
                                     ? q_map[(b * Hn + row) * Wn + col] : 0.f;
            }
        }
        float best1 = -1e30f, best2 = -1e30f;
        int r2 = 0; r1 = 0;
#pragma unroll
        for (int r = 0; r < Rn; ++r) {
            float s1 = b_g1[r], s2 = b_g2[r];
#pragma unroll
            for (int k = 0; k < 9; ++k) {
                s1 += q[k] * w_g1[r * 9 + k];
                s2 += q[k] * w_g2[r * 9 + k];
            }
            if (s1 > best1) { best1 = s1; r1 = r; }   // strict > == first argmax
            if (s2 > best2) { best2 = s2; r2 = r; }
        }
        if (half == 0) ridx2[w] = r2;
    }
    __syncthreads();

    // ---- phase 1: depthwise conv, 32 channels per thread, bf16 to LDS ----
    const bool okm = (h > 0);
    const bool okp = (h < Hn - 1);
    const float* xbase = x0 + (size_t)(b * Cn) * Hn * Wn + h * Wn + w;
    const int swz = (w & 7) << 4;

#pragma unroll 4
    for (int p = 0; p < 16; ++p) {                 // pairs of channels
        float tt[2];
#pragma unroll
        for (int u = 0; u < 2; ++u) {
            const int c = half * 32 + p * 2 + u;
            const float* xc = xbase + c * (Hn * Wn);
            float vm = okm ? xc[-Wn] : 0.f;
            float v0 = xc[0];
            float vp = okp ? xc[Wn] : 0.f;
            float lm = __shfl_up(vm, 1), l0 = __shfl_up(v0, 1), lp = __shfl_up(vp, 1);
            float rm = __shfl_down(vm, 1), r0 = __shfl_down(v0, 1), rp = __shfl_down(vp, 1);
            if (lane == 0) {
                if (w == 0) { lm = 0.f; l0 = 0.f; lp = 0.f; }
                else { lm = okm ? xc[-1 - Wn] : 0.f; l0 = xc[-1]; lp = okp ? xc[-1 + Wn] : 0.f; }
            }
            if (lane == 63) {
                if (w == 127) { rm = 0.f; r0 = 0.f; rp = 0.f; }
                else { rm = okm ? xc[1 - Wn] : 0.f; r0 = xc[1]; rp = okp ? xc[1 + Wn] : 0.f; }
            }
            const float* kp = &kern_lds[c * 48 + r1 * 12];
            float4 k03 = *(const float4*)kp;
            float4 k47 = *(const float4*)(kp + 4);
            float k8 = kp[8];
            float t = lm * k03.x + vm * k03.y + rm * k03.z
                    + l0 * k03.w + v0 * k47.x + r0 * k47.y
                    + lp * k47.z + vp * k47.w + rp * k8;
            tt[u] = leaky(t);
        }
        unsigned pk = (unsigned)bf16bits(tt[0]) | ((unsigned)bf16bits(tt[1]) << 16);
        int cbyte = (half * 32 + p * 2) * 2;
        *(unsigned*)((char*)t_lds + w * 128 + (cbyte ^ swz)) = pk;
    }
    __syncthreads();

    // ---- phase 2: MFMA channel mix + fused epilogue ----
    const int wv = tid >> 6;            // wave id = w-tile
    const int col = lane & 31;
    const int kh = lane >> 5;
    const int wn = wv * 32 + col;       // this lane's output column

    v8bf Bf[4];
#pragma unroll
    for (int ks = 0; ks < 4; ++ks) {
        int cbyte = (16 * ks + 8 * kh) * 2;
        Bf[ks] = *(const v8bf*)((const char*)t_lds + wn * 128 + (cbyte ^ ((wn & 7) << 4)));
    }

    v16f acc0, acc1;
#pragma unroll
    for (int i = 0; i < 16; ++i) { acc0[i] = 0.f; acc1[i] = 0.f; }

#pragma unroll
    for (int ks = 0; ks < 4; ++ks) {
        int cbyte = (16 * ks + 8 * kh) * 2;
        int o0 = col;                    // rows 0..31
        v8bf A0 = *(const v8bf*)((const char*)wc_lds + o0 * 128 + (cbyte ^ ((o0 & 7) << 4)));
        acc0 = __builtin_amdgcn_mfma_f32_32x32x16_bf16(A0, Bf[ks], acc0, 0, 0, 0);
        int o1 = 32 + col;               // rows 32..63
        v8bf A1 = *(const v8bf*)((const char*)wc_lds + o1 * 128 + (cbyte ^ ((o1 & 7) << 4)));
        acc1 = __builtin_amdgcn_mfma_f32_32x32x16_bf16(A1, Bf[ks], acc1, 0, 0, 0);
    }

    const int r2e = ridx2[wn];
    const float* xcol = x0 + ((size_t)(b * Cn) * Hn + h) * Wn + wn;
    float* ocol = out + ((size_t)(b * Cn) * Hn + h) * Wn + wn;

#pragma unroll
    for (int r = 0; r < 16; ++r) {
        int row = (r & 3) + 8 * (r >> 2) + 4 * kh;
        float xv = xcol[(size_t)row * (Hn * Wn)];
        float res = acc0[r] + bias_lds[row] + xv * att_lds[r2e * 68 + row];
        ocol[(size_t)row * (Hn * Wn)] = res;
    }
#pragma unroll
    for (int r = 0; r < 16; ++r) {
        int row = 32 + (r & 3) + 8 * (r >> 2) + 4 * kh;
        float xv = xcol[(size_t)row * (Hn * Wn)];
        float res = acc1[r] + bias_lds[row] + xv * att_lds[r2e * 68 + row];
        ocol[(size_t)row * (Hn * Wn)] = res;
    }
}

// ---------------------------------------------------------------------------
extern "C" void kernel_launch(void* const* d_in, const int* in_sizes, int n_in,
                              void* d_out, int out_size, void* d_ws, size_t ws_size,
                              hipStream_t stream)
{
    const float* x0     = (const float*)d_in[0];
    const float* deg    = (const float*)d_in[1];
    const float* q_map  = (const float*)d_in[2];
    const float* w_k1   = (const float*)d_in[3];
    const float* w_k2   = (const float*)d_in[4];
    const float* w_conv = (const float*)d_in[5];
    const float* b_conv = (const float*)d_in[6];
    const float* w_ca1  = (const float*)d_in[7];
    const float* w_ca2  = (const float*)d_in[8];
    const float* w_g1   = (const float*)d_in[9];
    const float* b_g1   = (const float*)d_in[10];
    const float* w_g2   = (const float*)d_in[11];
    const float* b_g2   = (const float*)d_in[12];
    float* outp   = (float*)d_out;
    float* kern_g = (float*)d_ws;                           // 8*2304 floats
    float* att_g  = kern_g + Bn * Cn * Rn * 9;              // 8*256 floats
    unsigned short* wbf = (unsigned short*)(att_g + Bn * 256);  // 4096 bf16

    precomp_kernel<<<Bn + 1, 256, 0, stream>>>(deg, w_k1, w_k2, w_ca1, w_ca2,
                                               w_conv, kern_g, att_g, wbf);
    da_main<<<Bn * Hn, 256, 0, stream>>>(x0, q_map, wbf, b_conv,
                                         w_g1, b_g1, w_g2, b_g2,
                                         kern_g, att_g, outp);
}